// Round 8
// baseline (338.943 us; speedup 1.0000x reference)
//
#include <hip/hip_runtime.h>

typedef short s16x4 __attribute__((ext_vector_type(4)));
typedef short s16x8 __attribute__((ext_vector_type(8)));
typedef float f32x2 __attribute__((ext_vector_type(2)));
typedef float f32x16 __attribute__((ext_vector_type(16)));
typedef unsigned int u32x4 __attribute__((ext_vector_type(4)));

#define HT_STRIDE 72  // bf16 row stride: 144 B = 9*16 -> 16B-aligned b128 rows

__device__ __forceinline__ unsigned short f2bf(float f) {
    unsigned int u = __float_as_uint(f);
    u += 0x7fffu + ((u >> 16) & 1u);
    return (unsigned short)(u >> 16);
}
__device__ __forceinline__ float bf2f(unsigned short h) {
    return __uint_as_float(((unsigned int)h) << 16);
}
__device__ __forceinline__ unsigned int pk2bf_rne(float lo, float hi) {
    unsigned int a = __float_as_uint(lo);
    a += 0x7fffu + ((a >> 16) & 1u);
    unsigned int b = __float_as_uint(hi);
    b += 0x7fffu + ((b >> 16) & 1u);
    return (a >> 16) | (b & 0xffff0000u);
}

// Factorization: T_l[(o,j),d] = sum_i W_l[o, i*64+j] * x[i,d]  (GEMM, K=i=64)
// A-frag layout (32x32x16, rows m = j_local, k = i), CONTIGUOUS per-wave stream:
//   slice G = (((l*4 + oh)*16 + oc)*2 + jt)*4 + ks   (o = 4*oc + oh)
//   Wp[G*512 + lane*8 + t] = bf16( W_l[o][ (16*ks + 8*(lane>>5) + t)*64 + jt*32 + (lane&31) ] )
// Prepack: block per (l,o): coalesced row load -> LDS -> conflict-free strided
// read -> coalesced 16B stores.
__global__ __launch_bounds__(256) void prepack_kernel(const float* __restrict__ W1,
                                                      const float* __restrict__ W2,
                                                      unsigned short* __restrict__ Wp) {
    __shared__ float sRow[4096]; // one W row, 16 KB
    const int blk = blockIdx.x;  // 0..127
    const int l = blk >> 6, o = blk & 63;
    const float* W = l ? W2 : W1;
    const float4* src = (const float4*)(W + o * 4096);
    float4* dstL = (float4*)sRow;
#pragma unroll
    for (int r = 0; r < 4; ++r)
        dstL[r * 256 + threadIdx.x] = src[r * 256 + threadIdx.x];
    __syncthreads();
    const int oh = o & 3, oc = o >> 2;
#pragma unroll
    for (int s = 0; s < 2; ++s) {
        int sl = s * 256 + threadIdx.x; // 0..511 <-> (jt, ks, lane)
        int lane = sl & 63;
        int ks = (sl >> 6) & 3;
        int jt = sl >> 8;
        int q2 = lane >> 5, n31 = lane & 31;
        const float* base = sRow + jt * 32 + n31;
        int i0 = 16 * ks + 8 * q2;
        u32x4 pv;
        pv[0] = pk2bf_rne(base[(i0 + 0) * 64], base[(i0 + 1) * 64]);
        pv[1] = pk2bf_rne(base[(i0 + 2) * 64], base[(i0 + 3) * 64]);
        pv[2] = pk2bf_rne(base[(i0 + 4) * 64], base[(i0 + 5) * 64]);
        pv[3] = pk2bf_rne(base[(i0 + 6) * 64], base[(i0 + 7) * 64]);
        int G = (((l * 4 + oh) * 16 + oc) * 2 + jt) * 4 + ks;
        ((u32x4*)Wp)[G * 64 + lane] = pv;
    }
}

// Block = 1 batch elem, 4 waves = 4 o-classes (o = 4*oc + oh). Grid 1024 ->
// 4 blocks/CU, 16 waves/CU (4/SIMD) for MFMA latency hiding.
// MFMA B-operand (k = i) is ALWAYS x, register-resident for the whole kernel;
// only the consume weights (j-factor: x, then h1) switch per layer.
// A-frags: contiguous per-wave L2 stream with 1-iteration prefetch.
__global__ __launch_bounds__(256, 4) void cin_kernel(const float* __restrict__ x,
                                                     const unsigned short* __restrict__ Wp,
                                                     const float* __restrict__ b1,
                                                     const float* __restrict__ b2,
                                                     const float* __restrict__ Wfc,
                                                     const float* __restrict__ bfc,
                                                     float* __restrict__ out) {
    // sH[l][d*72 + j]: layer-l j-factor source (l=0: x, l=1: h1), bf16 transposed
    __shared__ __align__(16) unsigned short sH[2][64 * HT_STRIDE]; // 18.4 KB
    __shared__ float sBias[128], sWfc[128], sRed[4];

    const int tid = threadIdx.x;
    const int oh = tid >> 6; // wave id = o-class
    const int lane = tid & 63;
    const int q2 = lane >> 5;
    const int n31 = lane & 31;
    const int bb = blockIdx.x;

    // ---- stage x: coalesced float4 reads (ALL 1024 float4) -> transposed bf16 LDS ----
    {
        const float4* xb4 = (const float4*)(x + bb * 4096);
#pragma unroll
        for (int rr = 0; rr < 4; ++rr) {
            int e4 = rr * 256 + tid;
            float4 v = xb4[e4];
            int e = e4 << 2;
            int f = e >> 6;     // field index (i / j)
            int d0 = e & 63;    // d-index
            sH[0][(d0 + 0) * HT_STRIDE + f] = f2bf(v.x);
            sH[0][(d0 + 1) * HT_STRIDE + f] = f2bf(v.y);
            sH[0][(d0 + 2) * HT_STRIDE + f] = f2bf(v.z);
            sH[0][(d0 + 3) * HT_STRIDE + f] = f2bf(v.w);
        }
    }
    if (tid < 128) {
        sBias[tid] = (tid < 64) ? b1[tid] : b2[tid - 64];
        sWfc[tid] = Wfc[tid];
    }
    __syncthreads();

    const f32x16 zz = {};
    float contrib = 0.0f;
    const s16x8* WpS8 = (const s16x8*)Wp;

    // ---- MFMA B-frags: B[k=i][n=d] = x[i,d] — fixed for BOTH layers ----
    s16x8 bfr[2][4]; // [nt][ks]
#pragma unroll
    for (int nt = 0; nt < 2; ++nt) {
        const int d = nt * 32 + n31;
#pragma unroll
        for (int ks = 0; ks < 4; ++ks)
            bfr[nt][ks] = *(const s16x8*)&sH[0][d * HT_STRIDE + 16 * ks + 8 * q2];
    }

    for (int l = 0; l < 2; ++l) {
        if (l) __syncthreads(); // h1 writes from all waves complete

        // ---- per-layer consume weights (j-factor) from sH[l] ----
        const unsigned short* hsrc = sH[l];
        f32x2 cw[2][2][8];  // [nt][jt][pair], acc regs r=2p,2p+1
#pragma unroll
        for (int nt = 0; nt < 2; ++nt) {
            const int d = nt * 32 + n31;
#pragma unroll
            for (int jt = 0; jt < 2; ++jt)
#pragma unroll
                for (int m = 0; m < 4; ++m) {
                    // acc rows r=4m..4m+3 -> j = jt*32 + 4*q2 + 8*m + (0..3)
                    s16x4 hv = *(const s16x4*)&hsrc[d * HT_STRIDE + jt * 32 + 4 * q2 + 8 * m];
                    cw[nt][jt][2 * m] = (f32x2){bf2f((unsigned short)hv[0]),
                                                bf2f((unsigned short)hv[1])};
                    cw[nt][jt][2 * m + 1] = (f32x2){bf2f((unsigned short)hv[2]),
                                                    bf2f((unsigned short)hv[3])};
                }
        }

        // ---- main loop: it = (oc, jt); o = 4*oc + oh; A-stream is contiguous ----
        const s16x8* pW = WpS8 + (l * 4 + oh) * 128 * 64 + lane; // slice stride 64
        s16x8 Areg[2][4];
#pragma unroll
        for (int ks = 0; ks < 4; ++ks) Areg[0][ks] = pW[ks * 64];
        f32x2 hp[2];

#pragma unroll 2
        for (int it = 0; it < 32; ++it) {
            const int jt = it & 1;
            const int o = 4 * (it >> 1) + oh;
            if (it < 31) { // prefetch next slice group (contiguous)
                const s16x8* p = pW + (it + 1) * 4 * 64;
#pragma unroll
                for (int ks = 0; ks < 4; ++ks) Areg[(it + 1) & 1][ks] = p[ks * 64];
            }
            const s16x8* A = Areg[it & 1];

            f32x16 a0 = __builtin_amdgcn_mfma_f32_32x32x16_bf16(A[0], bfr[0][0], zz, 0, 0, 0);
            f32x16 a1 = __builtin_amdgcn_mfma_f32_32x32x16_bf16(A[0], bfr[1][0], zz, 0, 0, 0);
#pragma unroll
            for (int ks = 1; ks < 4; ++ks) {
                a0 = __builtin_amdgcn_mfma_f32_32x32x16_bf16(A[ks], bfr[0][ks], a0, 0, 0, 0);
                a1 = __builtin_amdgcn_mfma_f32_32x32x16_bf16(A[ks], bfr[1][ks], a1, 0, 0, 0);
            }

            // consume T-tile: weighted column-sum over its 32 rows (j's)
#pragma unroll
            for (int nt = 0; nt < 2; ++nt) {
                const f32x2* a2 = nt ? (const f32x2*)&a1 : (const f32x2*)&a0;
                f32x2 s = a2[0] * cw[nt][jt][0];
#pragma unroll
                for (int p = 1; p < 8; ++p) s += a2[p] * cw[nt][jt][p];
                if (jt == 0) {
                    hp[nt] = s;
                } else {
                    f32x2 t2 = hp[nt] + s;
                    float hsum = t2.x + t2.y;
                    hsum += __shfl_xor(hsum, 32, 64); // partner q2-half rows
                    float v = fmaxf(hsum + sBias[l * 64 + o], 0.0f);
                    contrib += v * sWfc[l * 64 + o];
                    if (l == 0) // h1 handoff (both q2 halves write identical bits)
                        sH[1][(nt * 32 + n31) * HT_STRIDE + o] = f2bf(v);
                }
            }
        }
    }

    // each (o,d) accumulated by both q2 halves -> halve at the end
    contrib *= 0.5f;
#pragma unroll
    for (int off = 32; off > 0; off >>= 1)
        contrib += __shfl_down(contrib, off, 64);
    if (lane == 0) sRed[oh] = contrib;
    __syncthreads();
    if (tid == 0)
        out[bb] = sRed[0] + sRed[1] + sRed[2] + sRed[3] + bfc[0];
}

extern "C" void kernel_launch(void* const* d_in, const int* in_sizes, int n_in,
                              void* d_out, int out_size, void* d_ws, size_t ws_size,
                              hipStream_t stream) {
    const float* x = (const float*)d_in[0];
    const float* W1 = (const float*)d_in[1];
    const float* b1 = (const float*)d_in[2];
    const float* W2 = (const float*)d_in[3];
    const float* b2 = (const float*)d_in[4];
    const float* Wfc = (const float*)d_in[5];
    const float* bfc = (const float*)d_in[6];
    float* out = (float*)d_out;

    unsigned short* Wp = (unsigned short*)d_ws; // 524288 bf16 = 1 MB prepacked W'

    prepack_kernel<<<128, 256, 0, stream>>>(W1, W2, Wp);
    cin_kernel<<<1024, 256, 0, stream>>>(x, Wp, b1, b2, Wfc, bfc, out);
}

// Round 9
// 141.101 us; speedup vs baseline: 2.4021x; 2.4021x over previous
//
#include <hip/hip_runtime.h>

typedef short s16x4 __attribute__((ext_vector_type(4)));
typedef short s16x8 __attribute__((ext_vector_type(8)));
typedef float f32x2 __attribute__((ext_vector_type(2)));
typedef float f32x16 __attribute__((ext_vector_type(16)));
typedef unsigned int u32x4 __attribute__((ext_vector_type(4)));

#define HT_STRIDE 72  // bf16 row stride: 144 B = 9*16 -> 16B-aligned b128 rows

__device__ __forceinline__ unsigned short f2bf(float f) {
    unsigned int u = __float_as_uint(f);
    u += 0x7fffu + ((u >> 16) & 1u);
    return (unsigned short)(u >> 16);
}
__device__ __forceinline__ float bf2f(unsigned short h) {
    return __uint_as_float(((unsigned int)h) << 16);
}
__device__ __forceinline__ unsigned int pk2bf_rne(float lo, float hi) {
    unsigned int a = __float_as_uint(lo);
    a += 0x7fffu + ((a >> 16) & 1u);
    unsigned int b = __float_as_uint(hi);
    b += 0x7fffu + ((b >> 16) & 1u);
    return (a >> 16) | (b & 0xffff0000u);
}

// Factorization: T_l[(o,j),d] = sum_i W_l[o, i*64+j] * x[i,d]  (GEMM, K=i=64)
// A-frag layout (32x32x16, rows m = j_local, k = i), CONTIGUOUS per-wave stream:
//   slice G = (((l*4 + oh)*16 + oc)*2 + jt)*4 + ks   (o = 4*oc + oh)
//   Wp[G*512 + lane*8 + t] = bf16( W_l[o][ (16*ks + 8*(lane>>5) + t)*64 + jt*32 + (lane&31) ] )
__global__ __launch_bounds__(256) void prepack_kernel(const float* __restrict__ W1,
                                                      const float* __restrict__ W2,
                                                      unsigned short* __restrict__ Wp) {
    __shared__ float sRow[4096]; // one W row, 16 KB
    const int blk = blockIdx.x;  // 0..127
    const int l = blk >> 6, o = blk & 63;
    const float* W = l ? W2 : W1;
    const float4* src = (const float4*)(W + o * 4096);
    float4* dstL = (float4*)sRow;
#pragma unroll
    for (int r = 0; r < 4; ++r)
        dstL[r * 256 + threadIdx.x] = src[r * 256 + threadIdx.x];
    __syncthreads();
    const int oh = o & 3, oc = o >> 2;
#pragma unroll
    for (int s = 0; s < 2; ++s) {
        int sl = s * 256 + threadIdx.x; // 0..511 <-> (jt, ks, lane)
        int lane = sl & 63;
        int ks = (sl >> 6) & 3;
        int jt = sl >> 8;
        int q2 = lane >> 5, n31 = lane & 31;
        const float* base = sRow + jt * 32 + n31;
        int i0 = 16 * ks + 8 * q2;
        u32x4 pv;
        pv[0] = pk2bf_rne(base[(i0 + 0) * 64], base[(i0 + 1) * 64]);
        pv[1] = pk2bf_rne(base[(i0 + 2) * 64], base[(i0 + 3) * 64]);
        pv[2] = pk2bf_rne(base[(i0 + 4) * 64], base[(i0 + 5) * 64]);
        pv[3] = pk2bf_rne(base[(i0 + 6) * 64], base[(i0 + 7) * 64]);
        int G = (((l * 4 + oh) * 16 + oc) * 2 + jt) * 4 + ks;
        ((u32x4*)Wp)[G * 64 + lane] = pv;
    }
}

// Block = 1 batch elem, 4 waves = 4 o-classes (o = 4*oc + oh). Grid 1024 ->
// up to 4 blocks/CU (VGPR-permitting) for MFMA latency hiding.
// launch_bounds(256,2): do NOT cap registers below the ~140-reg working set —
// (256,4) in round 8 forced VGPR=64 and spilled 780 MB to scratch (6x slower).
__global__ __launch_bounds__(256, 2) void cin_kernel(const float* __restrict__ x,
                                                     const unsigned short* __restrict__ Wp,
                                                     const float* __restrict__ b1,
                                                     const float* __restrict__ b2,
                                                     const float* __restrict__ Wfc,
                                                     const float* __restrict__ bfc,
                                                     float* __restrict__ out) {
    // sH[l][d*72 + j]: layer-l j-factor source (l=0: x, l=1: h1), bf16 transposed
    __shared__ __align__(16) unsigned short sH[2][64 * HT_STRIDE]; // 18.4 KB
    __shared__ float sBias[128], sWfc[128], sRed[4];

    const int tid = threadIdx.x;
    const int oh = tid >> 6; // wave id = o-class
    const int lane = tid & 63;
    const int q2 = lane >> 5;
    const int n31 = lane & 31;
    const int bb = blockIdx.x;

    // ---- stage x: coalesced float4 reads (ALL 1024 float4) -> transposed bf16 LDS ----
    {
        const float4* xb4 = (const float4*)(x + bb * 4096);
#pragma unroll
        for (int rr = 0; rr < 4; ++rr) {
            int e4 = rr * 256 + tid;
            float4 v = xb4[e4];
            int e = e4 << 2;
            int f = e >> 6;     // field index (i / j)
            int d0 = e & 63;    // d-index
            sH[0][(d0 + 0) * HT_STRIDE + f] = f2bf(v.x);
            sH[0][(d0 + 1) * HT_STRIDE + f] = f2bf(v.y);
            sH[0][(d0 + 2) * HT_STRIDE + f] = f2bf(v.z);
            sH[0][(d0 + 3) * HT_STRIDE + f] = f2bf(v.w);
        }
    }
    if (tid < 128) {
        sBias[tid] = (tid < 64) ? b1[tid] : b2[tid - 64];
        sWfc[tid] = Wfc[tid];
    }
    __syncthreads();

    const f32x16 zz = {};
    float contrib = 0.0f;
    const s16x8* WpS8 = (const s16x8*)Wp;

    // ---- MFMA B-frags: B[k=i][n=d] = x[i,d] — fixed for BOTH layers ----
    s16x8 bfr[2][4]; // [nt][ks]
#pragma unroll
    for (int nt = 0; nt < 2; ++nt) {
        const int d = nt * 32 + n31;
#pragma unroll
        for (int ks = 0; ks < 4; ++ks)
            bfr[nt][ks] = *(const s16x8*)&sH[0][d * HT_STRIDE + 16 * ks + 8 * q2];
    }

    for (int l = 0; l < 2; ++l) {
        if (l) __syncthreads(); // h1 writes from all waves complete

        // ---- per-layer consume weights (j-factor) from sH[l] ----
        const unsigned short* hsrc = sH[l];
        f32x2 cw[2][2][8];  // [nt][jt][pair], acc regs r=2p,2p+1
#pragma unroll
        for (int nt = 0; nt < 2; ++nt) {
            const int d = nt * 32 + n31;
#pragma unroll
            for (int jt = 0; jt < 2; ++jt)
#pragma unroll
                for (int m = 0; m < 4; ++m) {
                    // acc rows r=4m..4m+3 -> j = jt*32 + 4*q2 + 8*m + (0..3)
                    s16x4 hv = *(const s16x4*)&hsrc[d * HT_STRIDE + jt * 32 + 4 * q2 + 8 * m];
                    cw[nt][jt][2 * m] = (f32x2){bf2f((unsigned short)hv[0]),
                                                bf2f((unsigned short)hv[1])};
                    cw[nt][jt][2 * m + 1] = (f32x2){bf2f((unsigned short)hv[2]),
                                                    bf2f((unsigned short)hv[3])};
                }
        }

        // ---- main loop: it = (oc, jt); o = 4*oc + oh; A-stream is contiguous ----
        const s16x8* pW = WpS8 + (l * 4 + oh) * 128 * 64 + lane; // slice stride 64
        s16x8 Areg[2][4];
#pragma unroll
        for (int ks = 0; ks < 4; ++ks) Areg[0][ks] = pW[ks * 64];
        f32x2 hp[2];

#pragma unroll 2
        for (int it = 0; it < 32; ++it) {
            const int jt = it & 1;
            const int o = 4 * (it >> 1) + oh;
            if (it < 31) { // prefetch next slice group (contiguous)
                const s16x8* p = pW + (it + 1) * 4 * 64;
#pragma unroll
                for (int ks = 0; ks < 4; ++ks) Areg[(it + 1) & 1][ks] = p[ks * 64];
            }
            const s16x8* A = Areg[it & 1];

            f32x16 a0 = __builtin_amdgcn_mfma_f32_32x32x16_bf16(A[0], bfr[0][0], zz, 0, 0, 0);
            f32x16 a1 = __builtin_amdgcn_mfma_f32_32x32x16_bf16(A[0], bfr[1][0], zz, 0, 0, 0);
#pragma unroll
            for (int ks = 1; ks < 4; ++ks) {
                a0 = __builtin_amdgcn_mfma_f32_32x32x16_bf16(A[ks], bfr[0][ks], a0, 0, 0, 0);
                a1 = __builtin_amdgcn_mfma_f32_32x32x16_bf16(A[ks], bfr[1][ks], a1, 0, 0, 0);
            }

            // consume T-tile: weighted column-sum over its 32 rows (j's)
#pragma unroll
            for (int nt = 0; nt < 2; ++nt) {
                const f32x2* a2 = nt ? (const f32x2*)&a1 : (const f32x2*)&a0;
                f32x2 s = a2[0] * cw[nt][jt][0];
#pragma unroll
                for (int p = 1; p < 8; ++p) s += a2[p] * cw[nt][jt][p];
                if (jt == 0) {
                    hp[nt] = s;
                } else {
                    f32x2 t2 = hp[nt] + s;
                    float hsum = t2.x + t2.y;
                    hsum += __shfl_xor(hsum, 32, 64); // partner q2-half rows
                    float v = fmaxf(hsum + sBias[l * 64 + o], 0.0f);
                    contrib += v * sWfc[l * 64 + o];
                    if (l == 0) // h1 handoff (both q2 halves write identical bits)
                        sH[1][(nt * 32 + n31) * HT_STRIDE + o] = f2bf(v);
                }
            }
        }
    }

    // each (o,d) accumulated by both q2 halves -> halve at the end
    contrib *= 0.5f;
#pragma unroll
    for (int off = 32; off > 0; off >>= 1)
        contrib += __shfl_down(contrib, off, 64);
    if (lane == 0) sRed[oh] = contrib;
    __syncthreads();
    if (tid == 0)
        out[bb] = sRed[0] + sRed[1] + sRed[2] + sRed[3] + bfc[0];
}

extern "C" void kernel_launch(void* const* d_in, const int* in_sizes, int n_in,
                              void* d_out, int out_size, void* d_ws, size_t ws_size,
                              hipStream_t stream) {
    const float* x = (const float*)d_in[0];
    const float* W1 = (const float*)d_in[1];
    const float* b1 = (const float*)d_in[2];
    const float* W2 = (const float*)d_in[3];
    const float* b2 = (const float*)d_in[4];
    const float* Wfc = (const float*)d_in[5];
    const float* bfc = (const float*)d_in[6];
    float* out = (float*)d_out;

    unsigned short* Wp = (unsigned short*)d_ws; // 524288 bf16 = 1 MB prepacked W'

    prepack_kernel<<<128, 256, 0, stream>>>(W1, W2, Wp);
    cin_kernel<<<1024, 256, 0, stream>>>(x, Wp, b1, b2, Wfc, bfc, out);
}